// Round 1
// baseline (442.398 us; speedup 1.0000x reference)
//
#include <hip/hip_runtime.h>
#include <hip/hip_bf16.h>

#define N_NODES 32000
#define FIN     128
#define E_EDGES 512000
#define EF_EDGES 544000
#define HC      64
#define NGRAPH  32
#define PROJ    8
#define OUT_DIM 256

// ---------------- degree count (int atomics) ----------------
__global__ __launch_bounds__(256) void deg_kernel(const int* __restrict__ ei,
                                                  int* __restrict__ deg) {
  int e = blockIdx.x * 256 + threadIdx.x;   // grid exactly E/256
  atomicAdd(&deg[ei[E_EDGES + e]], 1);
}

// ---------------- exclusive scan of deg+1 -> offs, next ----------------
__global__ __launch_bounds__(1024) void scan_kernel(const int* __restrict__ deg,
                                                    int* __restrict__ offs,
                                                    int* __restrict__ nxt) {
  __shared__ int part[1024];
  int t = threadIdx.x;
  int base = t * 32;
  int local[32];
  int s = 0;
#pragma unroll
  for (int i = 0; i < 32; ++i) {
    int idx = base + i;
    int v = (idx < N_NODES) ? (deg[idx] + 1) : 0;   // +1 self-loop
    local[i] = s;
    s += v;
  }
  part[t] = s;
  __syncthreads();
  for (int off = 1; off < 1024; off <<= 1) {
    int v = (t >= off) ? part[t - off] : 0;
    __syncthreads();
    part[t] += v;
    __syncthreads();
  }
  int pre = (t > 0) ? part[t - 1] : 0;
#pragma unroll
  for (int i = 0; i < 32; ++i) {
    int idx = base + i;
    if (idx < N_NODES) {
      int o = pre + local[i];
      offs[idx] = o;
      nxt[idx] = o;
    }
  }
  if (t == 1023) offs[N_NODES] = part[1023];
}

// ---------------- CSR fill (includes self-loops, eid>=E) ----------------
__global__ __launch_bounds__(256) void fill_kernel(const int* __restrict__ ei,
                                                   int* __restrict__ nxt,
                                                   int* __restrict__ csr_src,
                                                   int* __restrict__ csr_eid) {
  int e = blockIdx.x * 256 + threadIdx.x;   // grid exactly EF/256
  int s, d;
  if (e < E_EDGES) { s = ei[e]; d = ei[E_EDGES + e]; }
  else             { s = e - E_EDGES; d = s; }
  int pos = atomicAdd(&nxt[d], 1);
  csr_src[pos] = s;
  csr_eid[pos] = e;
}

// ---------------- self-loop attr = mean of incoming edge_attr ----------------
__global__ __launch_bounds__(256) void loopattr_kernel(const int* __restrict__ offs,
                                                       const int* __restrict__ csr_eid,
                                                       const float* __restrict__ ea,
                                                       float* __restrict__ loop_attr) {
  int lane = threadIdx.x & 63;
  int n = blockIdx.x * 4 + (threadIdx.x >> 6);
  int k = lane & 15, g = lane >> 4;
  int beg = offs[n], end = offs[n + 1];
  float s = 0.f;
  for (int i = beg + g; i < end; i += 4) {
    int e = csr_eid[i];
    if (e < E_EDGES) s += ea[(size_t)e * 16 + k];
  }
  s += __shfl_xor(s, 16);
  s += __shfl_xor(s, 32);
  int degv = end - beg - 1;  // real in-edges
  if (g == 0) loop_attr[(size_t)n * 16 + k] = s / fmaxf((float)degv, 1.f);
}

// ---------------- xl = A @ W ; fused al_s/al_d epilogue ----------------
template <int K>
__global__ __launch_bounds__(256) void transform_kernel(const float* __restrict__ A,
                                                        const float* __restrict__ W,
                                                        const float* __restrict__ a_s,
                                                        const float* __restrict__ a_d,
                                                        float* __restrict__ xl,
                                                        float* __restrict__ al_s,
                                                        float* __restrict__ al_d) {
  __shared__ float sW[64][64];
  __shared__ float sA[64][65];
  int tid = threadIdx.x;
  int row0 = blockIdx.x * 64;
  int tx = tid & 15, ty = tid >> 4;
  int c0 = tx * 4, r0 = ty * 4;
  float acc[4][4] = {};
  for (int kc = 0; kc < K; kc += 64) {
    for (int i = tid; i < 1024; i += 256) {
      int kk = i >> 4, c4 = (i & 15) * 4;
      *(float4*)&sW[kk][c4] = *(const float4*)&W[(size_t)(kc + kk) * HC + c4];
    }
    for (int i = tid; i < 1024; i += 256) {
      int r = i >> 4, k4 = (i & 15) * 4;
      float4 v = *(const float4*)&A[(size_t)(row0 + r) * K + kc + k4];
      sA[r][k4 + 0] = v.x; sA[r][k4 + 1] = v.y;
      sA[r][k4 + 2] = v.z; sA[r][k4 + 3] = v.w;
    }
    __syncthreads();
#pragma unroll 8
    for (int kk = 0; kk < 64; ++kk) {
      float4 w = *(float4*)&sW[kk][c0];
      float a0 = sA[r0 + 0][kk];
      float a1 = sA[r0 + 1][kk];
      float a2 = sA[r0 + 2][kk];
      float a3 = sA[r0 + 3][kk];
      acc[0][0] = fmaf(a0, w.x, acc[0][0]); acc[0][1] = fmaf(a0, w.y, acc[0][1]);
      acc[0][2] = fmaf(a0, w.z, acc[0][2]); acc[0][3] = fmaf(a0, w.w, acc[0][3]);
      acc[1][0] = fmaf(a1, w.x, acc[1][0]); acc[1][1] = fmaf(a1, w.y, acc[1][1]);
      acc[1][2] = fmaf(a1, w.z, acc[1][2]); acc[1][3] = fmaf(a1, w.w, acc[1][3]);
      acc[2][0] = fmaf(a2, w.x, acc[2][0]); acc[2][1] = fmaf(a2, w.y, acc[2][1]);
      acc[2][2] = fmaf(a2, w.z, acc[2][2]); acc[2][3] = fmaf(a2, w.w, acc[2][3]);
      acc[3][0] = fmaf(a3, w.x, acc[3][0]); acc[3][1] = fmaf(a3, w.y, acc[3][1]);
      acc[3][2] = fmaf(a3, w.z, acc[3][2]); acc[3][3] = fmaf(a3, w.w, acc[3][3]);
    }
    __syncthreads();
  }
  // a_s/a_d are [H,C] flat = 64; col c = h*16+cl maps directly.
  float asv[4], adv[4];
#pragma unroll
  for (int j = 0; j < 4; ++j) { asv[j] = a_s[c0 + j]; adv[j] = a_d[c0 + j]; }
  int hd = tx >> 2;
#pragma unroll
  for (int i = 0; i < 4; ++i) {
    int r = row0 + r0 + i;
    *(float4*)&xl[(size_t)r * HC + c0] =
        make_float4(acc[i][0], acc[i][1], acc[i][2], acc[i][3]);
    float ps = acc[i][0] * asv[0] + acc[i][1] * asv[1] + acc[i][2] * asv[2] + acc[i][3] * asv[3];
    float pd = acc[i][0] * adv[0] + acc[i][1] * adv[1] + acc[i][2] * adv[2] + acc[i][3] * adv[3];
    ps += __shfl_xor(ps, 1); ps += __shfl_xor(ps, 2);
    pd += __shfl_xor(pd, 1); pd += __shfl_xor(pd, 2);
    if ((tx & 3) == 0) {
      al_s[(size_t)r * 4 + hd] = ps;
      al_d[(size_t)r * 4 + hd] = pd;
    }
  }
}

// ---------------- al_e = ea_f @ M_e  (M_e folded from W_e,a_e) ----------------
__global__ __launch_bounds__(256) void al_e_kernel(const float* __restrict__ edge_attr,
                                                   const float* __restrict__ loop_attr,
                                                   const float* __restrict__ W_e,
                                                   const float* __restrict__ a_e,
                                                   float* __restrict__ al_e) {
  __shared__ float sMe[16][4];
  int tid = threadIdx.x;
  if (tid < 64) {
    int d = tid >> 2, h = tid & 3;
    float s = 0.f;
#pragma unroll
    for (int c = 0; c < 16; ++c) s += W_e[d * HC + h * 16 + c] * a_e[h * 16 + c];
    sMe[d][h] = s;
  }
  __syncthreads();
  int e = blockIdx.x * 256 + tid;   // grid exactly EF/256
  const float* ea = (e < E_EDGES) ? &edge_attr[(size_t)e * 16]
                                  : &loop_attr[(size_t)(e - E_EDGES) * 16];
  float4 v0 = *(const float4*)(ea + 0);
  float4 v1 = *(const float4*)(ea + 4);
  float4 v2 = *(const float4*)(ea + 8);
  float4 v3 = *(const float4*)(ea + 12);
  float r[4];
#pragma unroll
  for (int h = 0; h < 4; ++h) {
    r[h] = v0.x * sMe[0][h] + v0.y * sMe[1][h] + v0.z * sMe[2][h] + v0.w * sMe[3][h] +
           v1.x * sMe[4][h] + v1.y * sMe[5][h] + v1.z * sMe[6][h] + v1.w * sMe[7][h] +
           v2.x * sMe[8][h] + v2.y * sMe[9][h] + v2.z * sMe[10][h] + v2.w * sMe[11][h] +
           v3.x * sMe[12][h] + v3.y * sMe[13][h] + v3.z * sMe[14][h] + v3.w * sMe[15][h];
  }
  *(float4*)&al_e[(size_t)e * 4] = make_float4(r[0], r[1], r[2], r[3]);
}

// ---------------- per-dst softmax + aggregation (wave per node) ----------------
__global__ __launch_bounds__(256) void gather_kernel(const int* __restrict__ offs,
                                                     const int* __restrict__ csr_src,
                                                     const int* __restrict__ csr_eid,
                                                     const float* __restrict__ xl,
                                                     const float* __restrict__ al_s,
                                                     const float* __restrict__ al_d,
                                                     const float* __restrict__ al_e,
                                                     const float* __restrict__ bias,
                                                     float* __restrict__ hout) {
  int lane = threadIdx.x & 63;
  int n = blockIdx.x * 4 + (threadIdx.x >> 6);
  int hd = lane >> 4;
  int beg = offs[n], end = offs[n + 1];
  float ald = al_d[(size_t)n * 4 + hd];
  // pass 1: per-head max
  float m = -1e30f;
  for (int i = beg + (lane & 15); i < end; i += 16) {
    int s = csr_src[i];
    int e = csr_eid[i];
    float lg = al_s[(size_t)s * 4 + hd] + ald + al_e[(size_t)e * 4 + hd];
    lg = (lg > 0.f) ? lg : lg * 0.2f;
    m = fmaxf(m, lg);
  }
  m = fmaxf(m, __shfl_xor(m, 1));
  m = fmaxf(m, __shfl_xor(m, 2));
  m = fmaxf(m, __shfl_xor(m, 4));
  m = fmaxf(m, __shfl_xor(m, 8));
  // pass 2: exp/denom + weighted gather
  float denom = 0.f, acc = 0.f;
  for (int i = beg; i < end; ++i) {
    int s = csr_src[i];
    int e = csr_eid[i];
    float lg = al_s[(size_t)s * 4 + hd] + ald + al_e[(size_t)e * 4 + hd];
    lg = (lg > 0.f) ? lg : lg * 0.2f;
    float pex = __expf(lg - m);
    denom += pex;
    acc = fmaf(pex, xl[(size_t)s * HC + lane], acc);
  }
  hout[(size_t)n * HC + lane] = fmaxf(acc / denom + bias[lane], 0.f);
}

// ---------------- node projection 64 -> 8, relu ----------------
__global__ __launch_bounds__(256) void proj_kernel(const float* __restrict__ h,
                                                   const float* __restrict__ Wp,
                                                   const float* __restrict__ bp,
                                                   float* __restrict__ p) {
  int lane = threadIdx.x & 63;
  int n = blockIdx.x * 4 + (threadIdx.x >> 6);
  int j = lane & 7, cg = lane >> 3;
  float s = 0.f;
#pragma unroll
  for (int i = 0; i < 8; ++i) {
    int c = cg * 8 + i;
    s = fmaf(h[(size_t)n * HC + c], Wp[c * PROJ + j], s);
  }
  s += __shfl_xor(s, 8);
  s += __shfl_xor(s, 16);
  s += __shfl_xor(s, 32);
  if (cg == 0) p[(size_t)n * PROJ + j] = fmaxf(s + bp[j], 0.f);
}

// ---------------- fc_out stage 1: K-chunked partials ----------------
__global__ __launch_bounds__(256) void fc1_kernel(const float* __restrict__ p,
                                                  const float* __restrict__ Wo,
                                                  float* __restrict__ part) {
  __shared__ float sp[NGRAPH][250];
  int kc = blockIdx.x;   // 0..31, chunk of 250 K
  int ct = blockIdx.y;   // 0..3, 64 cols
  int tid = threadIdx.x;
  for (int i = tid; i < NGRAPH * 250; i += 256) {
    int g = i / 250, kk = i % 250;
    sp[g][kk] = p[(size_t)g * 8000 + kc * 250 + kk];
  }
  __syncthreads();
  int c = ct * 64 + (tid & 63);
  int kg = tid >> 6;   // wave id, wave-uniform
  float acc[NGRAPH] = {};
  for (int kk = kg; kk < 250; kk += 4) {
    float w = Wo[(size_t)(kc * 250 + kk) * OUT_DIM + c];
#pragma unroll
    for (int g = 0; g < NGRAPH; ++g) acc[g] = fmaf(sp[g][kk], w, acc[g]);
  }
  int ch = kc * 4 + kg;   // 0..127
#pragma unroll
  for (int g = 0; g < NGRAPH; ++g)
    part[((size_t)ch * NGRAPH + g) * OUT_DIM + c] = acc[g];
}

// ---------------- fc_out stage 2: reduce + bias ----------------
__global__ __launch_bounds__(256) void fc2_kernel(const float* __restrict__ part,
                                                  const float* __restrict__ bo,
                                                  float* __restrict__ out) {
  int i = blockIdx.x * 256 + threadIdx.x;   // 32*256 = 8192 exact
  int g = i >> 8, c = i & 255;
  float s = bo[c];
  for (int ch = 0; ch < 128; ++ch) s += part[((size_t)ch * NGRAPH + g) * OUT_DIM + c];
  out[i] = s;
}

extern "C" void kernel_launch(void* const* d_in, const int* in_sizes, int n_in,
                              void* d_out, int out_size, void* d_ws, size_t ws_size,
                              hipStream_t stream) {
  const float* x         = (const float*)d_in[0];
  const float* edge_attr = (const float*)d_in[1];
  const float* W0        = (const float*)d_in[2];
  const float* a_s0      = (const float*)d_in[3];
  const float* a_d0      = (const float*)d_in[4];
  const float* W_e0      = (const float*)d_in[5];
  const float* a_e0      = (const float*)d_in[6];
  const float* b0        = (const float*)d_in[7];
  const float* Wg        = (const float*)d_in[8];
  const float* a_sg      = (const float*)d_in[9];
  const float* a_dg      = (const float*)d_in[10];
  const float* W_eg      = (const float*)d_in[11];
  const float* a_eg      = (const float*)d_in[12];
  const float* bg        = (const float*)d_in[13];
  const float* Wp        = (const float*)d_in[14];
  const float* bp        = (const float*)d_in[15];
  const float* Wo        = (const float*)d_in[16];
  const float* bo        = (const float*)d_in[17];
  const int*   ei        = (const int*)d_in[18];

  // workspace carve-up (≈46 MB total)
  char* base = (char*)d_ws;
  size_t off = 0;
  auto alloc = [&](size_t bytes) -> void* {
    void* ptr = base + off;
    off = (off + bytes + 255) & ~(size_t)255;
    return ptr;
  };
  int*   deg       = (int*)alloc((size_t)N_NODES * 4);
  int*   offs      = (int*)alloc((size_t)(N_NODES + 1) * 4);
  int*   nxt       = (int*)alloc((size_t)N_NODES * 4);
  int*   csr_src   = (int*)alloc((size_t)EF_EDGES * 4);
  int*   csr_eid   = (int*)alloc((size_t)EF_EDGES * 4);
  float* loop_attr = (float*)alloc((size_t)N_NODES * 16 * 4);
  float* al_e      = (float*)alloc((size_t)EF_EDGES * 4 * 4);
  float* xl        = (float*)alloc((size_t)N_NODES * HC * 4);
  float* al_s      = (float*)alloc((size_t)N_NODES * 4 * 4);
  float* al_d      = (float*)alloc((size_t)N_NODES * 4 * 4);
  float* hA        = (float*)alloc((size_t)N_NODES * HC * 4);
  float* hB        = (float*)alloc((size_t)N_NODES * HC * 4);
  float* pbuf      = (float*)alloc((size_t)N_NODES * PROJ * 4);
  float* part      = (float*)alloc((size_t)128 * NGRAPH * OUT_DIM * 4);

  // ---- graph preprocessing (dst is layer-invariant) ----
  hipMemsetAsync(deg, 0, (size_t)N_NODES * 4, stream);
  deg_kernel<<<E_EDGES / 256, 256, 0, stream>>>(ei, deg);
  scan_kernel<<<1, 1024, 0, stream>>>(deg, offs, nxt);
  fill_kernel<<<EF_EDGES / 256, 256, 0, stream>>>(ei, nxt, csr_src, csr_eid);
  loopattr_kernel<<<N_NODES / 4, 256, 0, stream>>>(offs, csr_eid, edge_attr, loop_attr);

  // ---- layer 0: x(128) -> hA ----
  transform_kernel<FIN><<<N_NODES / 64, 256, 0, stream>>>(x, W0, a_s0, a_d0, xl, al_s, al_d);
  al_e_kernel<<<EF_EDGES / 256, 256, 0, stream>>>(edge_attr, loop_attr, W_e0, a_e0, al_e);
  gather_kernel<<<N_NODES / 4, 256, 0, stream>>>(offs, csr_src, csr_eid, xl, al_s, al_d, al_e, b0, hA);

  // ---- layer 1: hA -> hB ----
  transform_kernel<HC><<<N_NODES / 64, 256, 0, stream>>>(hA, Wg, a_sg, a_dg, xl, al_s, al_d);
  al_e_kernel<<<EF_EDGES / 256, 256, 0, stream>>>(edge_attr, loop_attr, W_eg, a_eg, al_e);
  gather_kernel<<<N_NODES / 4, 256, 0, stream>>>(offs, csr_src, csr_eid, xl, al_s, al_d, al_e, bg, hB);

  // ---- layer 2: hB -> hA ----
  transform_kernel<HC><<<N_NODES / 64, 256, 0, stream>>>(hB, Wg + HC * HC, a_sg + 64, a_dg + 64, xl, al_s, al_d);
  al_e_kernel<<<EF_EDGES / 256, 256, 0, stream>>>(edge_attr, loop_attr, W_eg + 16 * HC, a_eg + 64, al_e);
  gather_kernel<<<N_NODES / 4, 256, 0, stream>>>(offs, csr_src, csr_eid, xl, al_s, al_d, al_e, bg + 64, hA);

  // ---- head ----
  proj_kernel<<<N_NODES / 4, 256, 0, stream>>>(hA, Wp, bp, pbuf);
  fc1_kernel<<<dim3(32, 4), 256, 0, stream>>>(pbuf, Wo, part);
  fc2_kernel<<<NGRAPH, 256, 0, stream>>>(part, bo, (float*)d_out);
}

// Round 2
// 320.914 us; speedup vs baseline: 1.3786x; 1.3786x over previous
//
#include <hip/hip_runtime.h>
#include <hip/hip_bf16.h>

#define N_NODES 32000
#define FIN     128
#define E_EDGES 512000
#define EF_EDGES 544000
#define HC      64
#define NGRAPH  32
#define PROJ    8
#define OUT_DIM 256

// fp32 -> bf16 (RTNE) and back
static __device__ inline unsigned short f2bf(float f) {
  unsigned int x = __float_as_uint(f);
  unsigned int r = (x + 0x7fffu + ((x >> 16) & 1u)) >> 16;
  return (unsigned short)r;
}
static __device__ inline float bf2f(unsigned short u) {
  return __uint_as_float((unsigned int)u << 16);
}

// ---------------- degree count (int atomics) ----------------
__global__ __launch_bounds__(256) void deg_kernel(const int* __restrict__ ei,
                                                  int* __restrict__ deg) {
  int e = blockIdx.x * 256 + threadIdx.x;   // grid exactly E/256
  atomicAdd(&deg[ei[E_EDGES + e]], 1);
}

// ---------------- exclusive scan of deg+1 -> offs, next ----------------
__global__ __launch_bounds__(1024) void scan_kernel(const int* __restrict__ deg,
                                                    int* __restrict__ offs,
                                                    int* __restrict__ nxt) {
  __shared__ int part[1024];
  int t = threadIdx.x;
  int base = t * 32;
  int local[32];
  int s = 0;
#pragma unroll
  for (int i = 0; i < 32; ++i) {
    int idx = base + i;
    int v = (idx < N_NODES) ? (deg[idx] + 1) : 0;   // +1 self-loop
    local[i] = s;
    s += v;
  }
  part[t] = s;
  __syncthreads();
  for (int off = 1; off < 1024; off <<= 1) {
    int v = (t >= off) ? part[t - off] : 0;
    __syncthreads();
    part[t] += v;
    __syncthreads();
  }
  int pre = (t > 0) ? part[t - 1] : 0;
#pragma unroll
  for (int i = 0; i < 32; ++i) {
    int idx = base + i;
    if (idx < N_NODES) {
      int o = pre + local[i];
      offs[idx] = o;
      nxt[idx] = o;
    }
  }
  if (t == 1023) offs[N_NODES] = part[1023];
}

// ---------------- CSR fill (includes self-loops, eid>=E) + inverse map ----------------
__global__ __launch_bounds__(256) void fill_kernel(const int* __restrict__ ei,
                                                   int* __restrict__ nxt,
                                                   int* __restrict__ csr_src,
                                                   int* __restrict__ csr_eid,
                                                   int* __restrict__ csr_pos) {
  int e = blockIdx.x * 256 + threadIdx.x;   // grid exactly EF/256
  int s, d;
  if (e < E_EDGES) { s = ei[e]; d = ei[E_EDGES + e]; }
  else             { s = e - E_EDGES; d = s; }
  int pos = atomicAdd(&nxt[d], 1);
  csr_src[pos] = s;
  csr_eid[pos] = e;
  csr_pos[e] = pos;
}

// ---------------- self-loop attr = mean of incoming edge_attr ----------------
__global__ __launch_bounds__(256) void loopattr_kernel(const int* __restrict__ offs,
                                                       const int* __restrict__ csr_eid,
                                                       const float* __restrict__ ea,
                                                       float* __restrict__ loop_attr) {
  int lane = threadIdx.x & 63;
  int n = blockIdx.x * 4 + (threadIdx.x >> 6);
  int k = lane & 15, g = lane >> 4;
  int beg = offs[n], end = offs[n + 1];
  float s = 0.f;
  for (int i = beg + g; i < end; i += 4) {
    int e = csr_eid[i];
    if (e < E_EDGES) s += ea[(size_t)e * 16 + k];
  }
  s += __shfl_xor(s, 16);
  s += __shfl_xor(s, 32);
  int degv = end - beg - 1;  // real in-edges
  if (g == 0) loop_attr[(size_t)n * 16 + k] = s / fmaxf((float)degv, 1.f);
}

// ---------------- xl(bf16) = A @ W ; fused al_s/al_d epilogue ----------------
template <int K>
__global__ __launch_bounds__(256) void transform_kernel(const float* __restrict__ A,
                                                        const float* __restrict__ W,
                                                        const float* __restrict__ a_s,
                                                        const float* __restrict__ a_d,
                                                        unsigned short* __restrict__ xlb,
                                                        float* __restrict__ al_s,
                                                        float* __restrict__ al_d) {
  __shared__ float sW[64][64];
  __shared__ float sA[64][65];
  int tid = threadIdx.x;
  int row0 = blockIdx.x * 64;
  int tx = tid & 15, ty = tid >> 4;
  int c0 = tx * 4, r0 = ty * 4;
  float acc[4][4] = {};
  for (int kc = 0; kc < K; kc += 64) {
    for (int i = tid; i < 1024; i += 256) {
      int kk = i >> 4, c4 = (i & 15) * 4;
      *(float4*)&sW[kk][c4] = *(const float4*)&W[(size_t)(kc + kk) * HC + c4];
    }
    for (int i = tid; i < 1024; i += 256) {
      int r = i >> 4, k4 = (i & 15) * 4;
      float4 v = *(const float4*)&A[(size_t)(row0 + r) * K + kc + k4];
      sA[r][k4 + 0] = v.x; sA[r][k4 + 1] = v.y;
      sA[r][k4 + 2] = v.z; sA[r][k4 + 3] = v.w;
    }
    __syncthreads();
#pragma unroll 8
    for (int kk = 0; kk < 64; ++kk) {
      float4 w = *(float4*)&sW[kk][c0];
      float a0 = sA[r0 + 0][kk];
      float a1 = sA[r0 + 1][kk];
      float a2 = sA[r0 + 2][kk];
      float a3 = sA[r0 + 3][kk];
      acc[0][0] = fmaf(a0, w.x, acc[0][0]); acc[0][1] = fmaf(a0, w.y, acc[0][1]);
      acc[0][2] = fmaf(a0, w.z, acc[0][2]); acc[0][3] = fmaf(a0, w.w, acc[0][3]);
      acc[1][0] = fmaf(a1, w.x, acc[1][0]); acc[1][1] = fmaf(a1, w.y, acc[1][1]);
      acc[1][2] = fmaf(a1, w.z, acc[1][2]); acc[1][3] = fmaf(a1, w.w, acc[1][3]);
      acc[2][0] = fmaf(a2, w.x, acc[2][0]); acc[2][1] = fmaf(a2, w.y, acc[2][1]);
      acc[2][2] = fmaf(a2, w.z, acc[2][2]); acc[2][3] = fmaf(a2, w.w, acc[2][3]);
      acc[3][0] = fmaf(a3, w.x, acc[3][0]); acc[3][1] = fmaf(a3, w.y, acc[3][1]);
      acc[3][2] = fmaf(a3, w.z, acc[3][2]); acc[3][3] = fmaf(a3, w.w, acc[3][3]);
    }
    __syncthreads();
  }
  float asv[4], adv[4];
#pragma unroll
  for (int j = 0; j < 4; ++j) { asv[j] = a_s[c0 + j]; adv[j] = a_d[c0 + j]; }
  int hd = tx >> 2;
#pragma unroll
  for (int i = 0; i < 4; ++i) {
    int r = row0 + r0 + i;
    ushort4 u = make_ushort4(f2bf(acc[i][0]), f2bf(acc[i][1]),
                             f2bf(acc[i][2]), f2bf(acc[i][3]));
    *(ushort4*)&xlb[(size_t)r * HC + c0] = u;
    float ps = acc[i][0] * asv[0] + acc[i][1] * asv[1] + acc[i][2] * asv[2] + acc[i][3] * asv[3];
    float pd = acc[i][0] * adv[0] + acc[i][1] * adv[1] + acc[i][2] * adv[2] + acc[i][3] * adv[3];
    ps += __shfl_xor(ps, 1); ps += __shfl_xor(ps, 2);
    pd += __shfl_xor(pd, 1); pd += __shfl_xor(pd, 2);
    if ((tx & 3) == 0) {
      al_s[(size_t)r * 4 + hd] = ps;
      al_d[(size_t)r * 4 + hd] = pd;
    }
  }
}

// ---------------- lg0[pos] = al_s[src] + ea_f @ M_e  (CSR-ordered) ----------------
__global__ __launch_bounds__(256) void logit_kernel(const float* __restrict__ edge_attr,
                                                    const float* __restrict__ loop_attr,
                                                    const float* __restrict__ W_e,
                                                    const float* __restrict__ a_e,
                                                    const int* __restrict__ ei,
                                                    const int* __restrict__ csr_pos,
                                                    const float* __restrict__ al_s,
                                                    float* __restrict__ lg0) {
  __shared__ float sMe[16][4];
  int tid = threadIdx.x;
  if (tid < 64) {
    int d = tid >> 2, h = tid & 3;
    float s = 0.f;
#pragma unroll
    for (int c = 0; c < 16; ++c) s += W_e[d * HC + h * 16 + c] * a_e[h * 16 + c];
    sMe[d][h] = s;
  }
  __syncthreads();
  int e = blockIdx.x * 256 + tid;   // grid exactly EF/256
  int src;
  const float* ea;
  if (e < E_EDGES) { src = ei[e];          ea = &edge_attr[(size_t)e * 16]; }
  else             { src = e - E_EDGES;    ea = &loop_attr[(size_t)(e - E_EDGES) * 16]; }
  float4 v0 = *(const float4*)(ea + 0);
  float4 v1 = *(const float4*)(ea + 4);
  float4 v2 = *(const float4*)(ea + 8);
  float4 v3 = *(const float4*)(ea + 12);
  float4 als = *(const float4*)&al_s[(size_t)src * 4];
  float r[4];
#pragma unroll
  for (int h = 0; h < 4; ++h) {
    r[h] = v0.x * sMe[0][h] + v0.y * sMe[1][h] + v0.z * sMe[2][h] + v0.w * sMe[3][h] +
           v1.x * sMe[4][h] + v1.y * sMe[5][h] + v1.z * sMe[6][h] + v1.w * sMe[7][h] +
           v2.x * sMe[8][h] + v2.y * sMe[9][h] + v2.z * sMe[10][h] + v2.w * sMe[11][h] +
           v3.x * sMe[12][h] + v3.y * sMe[13][h] + v3.z * sMe[14][h] + v3.w * sMe[15][h];
  }
  int pos = csr_pos[e];
  *(float4*)&lg0[(size_t)pos * 4] =
      make_float4(r[0] + als.x, r[1] + als.y, r[2] + als.z, r[3] + als.w);
}

// ---------------- one-pass online softmax + aggregation (wave per node) ----------------
template <int FUSE_PROJ>
__global__ __launch_bounds__(256) void gather_kernel(const int* __restrict__ offs,
                                                     const int* __restrict__ csr_src,
                                                     const float* __restrict__ lg0,
                                                     const unsigned short* __restrict__ xlb,
                                                     const float* __restrict__ al_d,
                                                     const float* __restrict__ bias,
                                                     const float* __restrict__ Wp,
                                                     const float* __restrict__ bp,
                                                     float* __restrict__ outp) {
  int lane = threadIdx.x & 63;
  int n = blockIdx.x * 4 + (threadIdx.x >> 6);
  int hd = lane >> 4;
  int beg = offs[n], end = offs[n + 1];
  float ald = al_d[(size_t)n * 4 + hd];
  float m = -1e30f, denom = 0.f, acc = 0.f;
  int i = beg;
  for (; i + 4 <= end; i += 4) {
    int s0 = csr_src[i + 0];
    int s1 = csr_src[i + 1];
    int s2 = csr_src[i + 2];
    int s3 = csr_src[i + 3];
    float l0 = lg0[(size_t)(i + 0) * 4 + hd] + ald;
    float l1 = lg0[(size_t)(i + 1) * 4 + hd] + ald;
    float l2 = lg0[(size_t)(i + 2) * 4 + hd] + ald;
    float l3 = lg0[(size_t)(i + 3) * 4 + hd] + ald;
    l0 = (l0 > 0.f) ? l0 : 0.2f * l0;
    l1 = (l1 > 0.f) ? l1 : 0.2f * l1;
    l2 = (l2 > 0.f) ? l2 : 0.2f * l2;
    l3 = (l3 > 0.f) ? l3 : 0.2f * l3;
    unsigned short x0 = xlb[(size_t)s0 * HC + lane];
    unsigned short x1 = xlb[(size_t)s1 * HC + lane];
    unsigned short x2 = xlb[(size_t)s2 * HC + lane];
    unsigned short x3 = xlb[(size_t)s3 * HC + lane];
    float mx = fmaxf(fmaxf(fmaxf(l0, l1), fmaxf(l2, l3)), m);
    float sc = __expf(m - mx);
    float p0 = __expf(l0 - mx);
    float p1 = __expf(l1 - mx);
    float p2 = __expf(l2 - mx);
    float p3 = __expf(l3 - mx);
    denom = denom * sc + ((p0 + p1) + (p2 + p3));
    acc = acc * sc + p0 * bf2f(x0) + p1 * bf2f(x1) + p2 * bf2f(x2) + p3 * bf2f(x3);
    m = mx;
  }
  for (; i < end; ++i) {
    int s = csr_src[i];
    float l = lg0[(size_t)i * 4 + hd] + ald;
    l = (l > 0.f) ? l : 0.2f * l;
    float mx = fmaxf(m, l);
    float sc = __expf(m - mx);
    float p = __expf(l - mx);
    denom = denom * sc + p;
    acc = acc * sc + p * bf2f(xlb[(size_t)s * HC + lane]);
    m = mx;
  }
  float hv = fmaxf(acc / denom + bias[lane], 0.f);
  if constexpr (!FUSE_PROJ) {
    outp[(size_t)n * HC + lane] = hv;
  } else {
    // p_j = relu(sum_c hv_c * Wp[c][j] + bp[j]), j = 0..7, reduced across the wave
    float pj[8];
#pragma unroll
    for (int j = 0; j < 8; ++j) pj[j] = hv * Wp[lane * PROJ + j];
#pragma unroll
    for (int off = 1; off < 64; off <<= 1) {
#pragma unroll
      for (int j = 0; j < 8; ++j) pj[j] += __shfl_xor(pj[j], off);
    }
    if (lane < 8) {
      float v = pj[0];
      v = (lane == 1) ? pj[1] : v;
      v = (lane == 2) ? pj[2] : v;
      v = (lane == 3) ? pj[3] : v;
      v = (lane == 4) ? pj[4] : v;
      v = (lane == 5) ? pj[5] : v;
      v = (lane == 6) ? pj[6] : v;
      v = (lane == 7) ? pj[7] : v;
      outp[(size_t)n * PROJ + lane] = fmaxf(v + bp[lane], 0.f);
    }
  }
}

// ---------------- fc_out stage 1: K-chunked partials ----------------
__global__ __launch_bounds__(256) void fc1_kernel(const float* __restrict__ p,
                                                  const float* __restrict__ Wo,
                                                  float* __restrict__ part) {
  __shared__ float sp[NGRAPH][250];
  int kc = blockIdx.x;   // 0..31, chunk of 250 K
  int ct = blockIdx.y;   // 0..3, 64 cols
  int tid = threadIdx.x;
  for (int i = tid; i < NGRAPH * 250; i += 256) {
    int g = i / 250, kk = i % 250;
    sp[g][kk] = p[(size_t)g * 8000 + kc * 250 + kk];
  }
  __syncthreads();
  int c = ct * 64 + (tid & 63);
  int kg = tid >> 6;   // wave id, wave-uniform
  float acc[NGRAPH] = {};
  for (int kk = kg; kk < 250; kk += 4) {
    float w = Wo[(size_t)(kc * 250 + kk) * OUT_DIM + c];
#pragma unroll
    for (int g = 0; g < NGRAPH; ++g) acc[g] = fmaf(sp[g][kk], w, acc[g]);
  }
  int ch = kc * 4 + kg;   // 0..127
#pragma unroll
  for (int g = 0; g < NGRAPH; ++g)
    part[((size_t)ch * NGRAPH + g) * OUT_DIM + c] = acc[g];
}

// ---------------- fc_out stage 2: reduce + bias ----------------
__global__ __launch_bounds__(256) void fc2_kernel(const float* __restrict__ part,
                                                  const float* __restrict__ bo,
                                                  float* __restrict__ out) {
  int i = blockIdx.x * 256 + threadIdx.x;   // 32*256 = 8192 exact
  int g = i >> 8, c = i & 255;
  float s = bo[c];
  for (int ch = 0; ch < 128; ++ch) s += part[((size_t)ch * NGRAPH + g) * OUT_DIM + c];
  out[i] = s;
}

extern "C" void kernel_launch(void* const* d_in, const int* in_sizes, int n_in,
                              void* d_out, int out_size, void* d_ws, size_t ws_size,
                              hipStream_t stream) {
  const float* x         = (const float*)d_in[0];
  const float* edge_attr = (const float*)d_in[1];
  const float* W0        = (const float*)d_in[2];
  const float* a_s0      = (const float*)d_in[3];
  const float* a_d0      = (const float*)d_in[4];
  const float* W_e0      = (const float*)d_in[5];
  const float* a_e0      = (const float*)d_in[6];
  const float* b0        = (const float*)d_in[7];
  const float* Wg        = (const float*)d_in[8];
  const float* a_sg      = (const float*)d_in[9];
  const float* a_dg      = (const float*)d_in[10];
  const float* W_eg      = (const float*)d_in[11];
  const float* a_eg      = (const float*)d_in[12];
  const float* bg        = (const float*)d_in[13];
  const float* Wp        = (const float*)d_in[14];
  const float* bp        = (const float*)d_in[15];
  const float* Wo        = (const float*)d_in[16];
  const float* bo        = (const float*)d_in[17];
  const int*   ei        = (const int*)d_in[18];

  char* base = (char*)d_ws;
  size_t off = 0;
  auto alloc = [&](size_t bytes) -> void* {
    void* ptr = base + off;
    off = (off + bytes + 255) & ~(size_t)255;
    return ptr;
  };
  int*            deg       = (int*)alloc((size_t)N_NODES * 4);
  int*            offs      = (int*)alloc((size_t)(N_NODES + 1) * 4);
  int*            nxt       = (int*)alloc((size_t)N_NODES * 4);
  int*            csr_src   = (int*)alloc((size_t)EF_EDGES * 4);
  int*            csr_eid   = (int*)alloc((size_t)EF_EDGES * 4);
  int*            csr_pos   = (int*)alloc((size_t)EF_EDGES * 4);
  float*          loop_attr = (float*)alloc((size_t)N_NODES * 16 * 4);
  float*          lg0       = (float*)alloc((size_t)EF_EDGES * 4 * 4);
  unsigned short* xlb       = (unsigned short*)alloc((size_t)N_NODES * HC * 2);
  float*          al_s      = (float*)alloc((size_t)N_NODES * 4 * 4);
  float*          al_d      = (float*)alloc((size_t)N_NODES * 4 * 4);
  float*          hA        = (float*)alloc((size_t)N_NODES * HC * 4);
  float*          hB        = (float*)alloc((size_t)N_NODES * HC * 4);
  float*          pbuf      = (float*)alloc((size_t)N_NODES * PROJ * 4);
  float*          part      = (float*)alloc((size_t)128 * NGRAPH * OUT_DIM * 4);

  // ---- graph preprocessing (dst is layer-invariant) ----
  hipMemsetAsync(deg, 0, (size_t)N_NODES * 4, stream);
  deg_kernel<<<E_EDGES / 256, 256, 0, stream>>>(ei, deg);
  scan_kernel<<<1, 1024, 0, stream>>>(deg, offs, nxt);
  fill_kernel<<<EF_EDGES / 256, 256, 0, stream>>>(ei, nxt, csr_src, csr_eid, csr_pos);
  loopattr_kernel<<<N_NODES / 4, 256, 0, stream>>>(offs, csr_eid, edge_attr, loop_attr);

  // ---- layer 0: x(128) -> hA ----
  transform_kernel<FIN><<<N_NODES / 64, 256, 0, stream>>>(x, W0, a_s0, a_d0, xlb, al_s, al_d);
  logit_kernel<<<EF_EDGES / 256, 256, 0, stream>>>(edge_attr, loop_attr, W_e0, a_e0, ei, csr_pos, al_s, lg0);
  gather_kernel<0><<<N_NODES / 4, 256, 0, stream>>>(offs, csr_src, lg0, xlb, al_d, b0, Wp, bp, hA);

  // ---- layer 1: hA -> hB ----
  transform_kernel<HC><<<N_NODES / 64, 256, 0, stream>>>(hA, Wg, a_sg, a_dg, xlb, al_s, al_d);
  logit_kernel<<<EF_EDGES / 256, 256, 0, stream>>>(edge_attr, loop_attr, W_eg, a_eg, ei, csr_pos, al_s, lg0);
  gather_kernel<0><<<N_NODES / 4, 256, 0, stream>>>(offs, csr_src, lg0, xlb, al_d, bg, Wp, bp, hB);

  // ---- layer 2: hB -> pbuf (proj fused) ----
  transform_kernel<HC><<<N_NODES / 64, 256, 0, stream>>>(hB, Wg + HC * HC, a_sg + 64, a_dg + 64, xlb, al_s, al_d);
  logit_kernel<<<EF_EDGES / 256, 256, 0, stream>>>(edge_attr, loop_attr, W_eg + 16 * HC, a_eg + 64, ei, csr_pos, al_s, lg0);
  gather_kernel<1><<<N_NODES / 4, 256, 0, stream>>>(offs, csr_src, lg0, xlb, al_d, bg + 64, Wp, bp, pbuf);

  // ---- head ----
  fc1_kernel<<<dim3(32, 4), 256, 0, stream>>>(pbuf, Wo, part);
  fc2_kernel<<<NGRAPH, 256, 0, stream>>>(part, bo, (float*)d_out);
}

// Round 3
// 278.845 us; speedup vs baseline: 1.5865x; 1.1509x over previous
//
#include <hip/hip_runtime.h>
#include <hip/hip_bf16.h>

#define N_NODES 32000
#define FIN     128
#define E_EDGES 512000
#define EF_EDGES 544000
#define HC      64
#define NGRAPH  32
#define PROJ    8
#define OUT_DIM 256

// fp32 -> bf16 (RTNE) and back
static __device__ inline unsigned short f2bf(float f) {
  unsigned int x = __float_as_uint(f);
  unsigned int r = (x + 0x7fffu + ((x >> 16) & 1u)) >> 16;
  return (unsigned short)r;
}
static __device__ inline float bf2f(unsigned short u) {
  return __uint_as_float((unsigned int)u << 16);
}

// ---------------- degree count (int atomics) ----------------
__global__ __launch_bounds__(256) void deg_kernel(const int* __restrict__ ei,
                                                  int* __restrict__ deg) {
  int e = blockIdx.x * 256 + threadIdx.x;   // grid exactly E/256
  atomicAdd(&deg[ei[E_EDGES + e]], 1);
}

// ---------------- multi-block scan of deg+1 ----------------
// phase 1: per-block exclusive scan + block sums
__global__ __launch_bounds__(256) void scan1_kernel(const int* __restrict__ deg,
                                                    int* __restrict__ offs,
                                                    int* __restrict__ bsum) {
  int idx = blockIdx.x * 256 + threadIdx.x;   // grid exactly 125
  int lane = threadIdx.x & 63;
  int w = threadIdx.x >> 6;
  int v = deg[idx] + 1;   // +1 self-loop
  int s = v;
#pragma unroll
  for (int off = 1; off < 64; off <<= 1) {
    int t = __shfl_up(s, off);
    if (lane >= off) s += t;
  }
  __shared__ int wsum[4];
  if (lane == 63) wsum[w] = s;
  __syncthreads();
  int add = 0;
#pragma unroll
  for (int i = 0; i < 4; ++i) add += (i < w) ? wsum[i] : 0;
  int incl = s + add;
  offs[idx] = incl - v;   // exclusive within block
  if (threadIdx.x == 255) bsum[blockIdx.x] = incl;
}

// phase 2: scan the 125 block sums (1 block)
__global__ __launch_bounds__(128) void scan2_kernel(const int* __restrict__ bsum,
                                                    int* __restrict__ boffs,
                                                    int* __restrict__ offs) {
  int t = threadIdx.x;
  int lane = t & 63;
  int w = t >> 6;
  int v = (t < 125) ? bsum[t] : 0;
  int s = v;
#pragma unroll
  for (int off = 1; off < 64; off <<= 1) {
    int tt = __shfl_up(s, off);
    if (lane >= off) s += tt;
  }
  __shared__ int wsum[2];
  if (lane == 63) wsum[w] = s;
  __syncthreads();
  int incl = s + ((w == 1) ? wsum[0] : 0);
  if (t < 125) boffs[t] = incl - v;
  if (t == 127) offs[N_NODES] = incl;   // grand total = EF_EDGES
}

// phase 3: add block offsets, fill cursor array
__global__ __launch_bounds__(256) void scan3_kernel(const int* __restrict__ boffs,
                                                    int* __restrict__ offs,
                                                    int* __restrict__ nxt) {
  int idx = blockIdx.x * 256 + threadIdx.x;
  int o = offs[idx] + boffs[blockIdx.x];
  offs[idx] = o;
  nxt[idx] = o;
}

// ---------------- CSR fill (includes self-loops, eid>=E) + inverse map ----------------
__global__ __launch_bounds__(256) void fill_kernel(const int* __restrict__ ei,
                                                   int* __restrict__ nxt,
                                                   int* __restrict__ csr_src,
                                                   int* __restrict__ csr_eid,
                                                   int* __restrict__ csr_pos) {
  int e = blockIdx.x * 256 + threadIdx.x;   // grid exactly EF/256
  int s, d;
  if (e < E_EDGES) { s = ei[e]; d = ei[E_EDGES + e]; }
  else             { s = e - E_EDGES; d = s; }
  int pos = atomicAdd(&nxt[d], 1);
  csr_src[pos] = s;
  csr_eid[pos] = e;
  csr_pos[e] = pos;
}

// ---------------- self-loop attr = mean of incoming edge_attr ----------------
__global__ __launch_bounds__(256) void loopattr_kernel(const int* __restrict__ offs,
                                                       const int* __restrict__ csr_eid,
                                                       const float* __restrict__ ea,
                                                       float* __restrict__ loop_attr) {
  int lane = threadIdx.x & 63;
  int n = blockIdx.x * 4 + (threadIdx.x >> 6);
  int k = lane & 15, g = lane >> 4;
  int beg = offs[n], end = offs[n + 1];
  float s = 0.f;
  for (int i = beg + g; i < end; i += 4) {
    int e = csr_eid[i];
    if (e < E_EDGES) s += ea[(size_t)e * 16 + k];
  }
  s += __shfl_xor(s, 16);
  s += __shfl_xor(s, 32);
  int degv = end - beg - 1;  // real in-edges
  if (g == 0) loop_attr[(size_t)n * 16 + k] = s / fmaxf((float)degv, 1.f);
}

// ---------------- xl(bf16) = A @ W ; fused al_s/al_d epilogue ----------------
template <int K>
__global__ __launch_bounds__(256) void transform_kernel(const float* __restrict__ A,
                                                        const float* __restrict__ W,
                                                        const float* __restrict__ a_s,
                                                        const float* __restrict__ a_d,
                                                        unsigned short* __restrict__ xlb,
                                                        float* __restrict__ al_s,
                                                        float* __restrict__ al_d) {
  __shared__ float sW[64][64];
  __shared__ float sA[64][65];
  int tid = threadIdx.x;
  int row0 = blockIdx.x * 64;
  int tx = tid & 15, ty = tid >> 4;
  int c0 = tx * 4, r0 = ty * 4;
  float acc[4][4] = {};
  for (int kc = 0; kc < K; kc += 64) {
    for (int i = tid; i < 1024; i += 256) {
      int kk = i >> 4, c4 = (i & 15) * 4;
      *(float4*)&sW[kk][c4] = *(const float4*)&W[(size_t)(kc + kk) * HC + c4];
    }
    for (int i = tid; i < 1024; i += 256) {
      int r = i >> 4, k4 = (i & 15) * 4;
      float4 v = *(const float4*)&A[(size_t)(row0 + r) * K + kc + k4];
      sA[r][k4 + 0] = v.x; sA[r][k4 + 1] = v.y;
      sA[r][k4 + 2] = v.z; sA[r][k4 + 3] = v.w;
    }
    __syncthreads();
#pragma unroll 8
    for (int kk = 0; kk < 64; ++kk) {
      float4 w = *(float4*)&sW[kk][c0];
      float a0 = sA[r0 + 0][kk];
      float a1 = sA[r0 + 1][kk];
      float a2 = sA[r0 + 2][kk];
      float a3 = sA[r0 + 3][kk];
      acc[0][0] = fmaf(a0, w.x, acc[0][0]); acc[0][1] = fmaf(a0, w.y, acc[0][1]);
      acc[0][2] = fmaf(a0, w.z, acc[0][2]); acc[0][3] = fmaf(a0, w.w, acc[0][3]);
      acc[1][0] = fmaf(a1, w.x, acc[1][0]); acc[1][1] = fmaf(a1, w.y, acc[1][1]);
      acc[1][2] = fmaf(a1, w.z, acc[1][2]); acc[1][3] = fmaf(a1, w.w, acc[1][3]);
      acc[2][0] = fmaf(a2, w.x, acc[2][0]); acc[2][1] = fmaf(a2, w.y, acc[2][1]);
      acc[2][2] = fmaf(a2, w.z, acc[2][2]); acc[2][3] = fmaf(a2, w.w, acc[2][3]);
      acc[3][0] = fmaf(a3, w.x, acc[3][0]); acc[3][1] = fmaf(a3, w.y, acc[3][1]);
      acc[3][2] = fmaf(a3, w.z, acc[3][2]); acc[3][3] = fmaf(a3, w.w, acc[3][3]);
    }
    __syncthreads();
  }
  float asv[4], adv[4];
#pragma unroll
  for (int j = 0; j < 4; ++j) { asv[j] = a_s[c0 + j]; adv[j] = a_d[c0 + j]; }
  int hd = tx >> 2;
#pragma unroll
  for (int i = 0; i < 4; ++i) {
    int r = row0 + r0 + i;
    ushort4 u = make_ushort4(f2bf(acc[i][0]), f2bf(acc[i][1]),
                             f2bf(acc[i][2]), f2bf(acc[i][3]));
    *(ushort4*)&xlb[(size_t)r * HC + c0] = u;
    float ps = acc[i][0] * asv[0] + acc[i][1] * asv[1] + acc[i][2] * asv[2] + acc[i][3] * asv[3];
    float pd = acc[i][0] * adv[0] + acc[i][1] * adv[1] + acc[i][2] * adv[2] + acc[i][3] * adv[3];
    ps += __shfl_xor(ps, 1); ps += __shfl_xor(ps, 2);
    pd += __shfl_xor(pd, 1); pd += __shfl_xor(pd, 2);
    if ((tx & 3) == 0) {
      al_s[(size_t)r * 4 + hd] = ps;
      al_d[(size_t)r * 4 + hd] = pd;
    }
  }
}

// ---------------- lg0[pos] = al_s[src] + ea_f @ M_e  (CSR-ordered) ----------------
__global__ __launch_bounds__(256) void logit_kernel(const float* __restrict__ edge_attr,
                                                    const float* __restrict__ loop_attr,
                                                    const float* __restrict__ W_e,
                                                    const float* __restrict__ a_e,
                                                    const int* __restrict__ ei,
                                                    const int* __restrict__ csr_pos,
                                                    const float* __restrict__ al_s,
                                                    float* __restrict__ lg0) {
  __shared__ float sMe[16][4];
  int tid = threadIdx.x;
  if (tid < 64) {
    int d = tid >> 2, h = tid & 3;
    float s = 0.f;
#pragma unroll
    for (int c = 0; c < 16; ++c) s += W_e[d * HC + h * 16 + c] * a_e[h * 16 + c];
    sMe[d][h] = s;
  }
  __syncthreads();
  int e = blockIdx.x * 256 + tid;   // grid exactly EF/256
  int src;
  const float* ea;
  if (e < E_EDGES) { src = ei[e];          ea = &edge_attr[(size_t)e * 16]; }
  else             { src = e - E_EDGES;    ea = &loop_attr[(size_t)(e - E_EDGES) * 16]; }
  float4 v0 = *(const float4*)(ea + 0);
  float4 v1 = *(const float4*)(ea + 4);
  float4 v2 = *(const float4*)(ea + 8);
  float4 v3 = *(const float4*)(ea + 12);
  float4 als = *(const float4*)&al_s[(size_t)src * 4];
  float r[4];
#pragma unroll
  for (int h = 0; h < 4; ++h) {
    r[h] = v0.x * sMe[0][h] + v0.y * sMe[1][h] + v0.z * sMe[2][h] + v0.w * sMe[3][h] +
           v1.x * sMe[4][h] + v1.y * sMe[5][h] + v1.z * sMe[6][h] + v1.w * sMe[7][h] +
           v2.x * sMe[8][h] + v2.y * sMe[9][h] + v2.z * sMe[10][h] + v2.w * sMe[11][h] +
           v3.x * sMe[12][h] + v3.y * sMe[13][h] + v3.z * sMe[14][h] + v3.w * sMe[15][h];
  }
  int pos = csr_pos[e];
  *(float4*)&lg0[(size_t)pos * 4] =
      make_float4(r[0] + als.x, r[1] + als.y, r[2] + als.z, r[3] + als.w);
}

// ---------------- one-pass online softmax + aggregation (wave per node) ----------------
template <int FUSE_PROJ>
__global__ __launch_bounds__(256) void gather_kernel(const int* __restrict__ offs,
                                                     const int* __restrict__ csr_src,
                                                     const float* __restrict__ lg0,
                                                     const unsigned short* __restrict__ xlb,
                                                     const float* __restrict__ al_d,
                                                     const float* __restrict__ bias,
                                                     const float* __restrict__ Wp,
                                                     const float* __restrict__ bp,
                                                     float* __restrict__ outp) {
  int lane = threadIdx.x & 63;
  int n = blockIdx.x * 4 + (threadIdx.x >> 6);
  int hd = lane >> 4;
  int beg = offs[n], end = offs[n + 1];
  float ald = al_d[(size_t)n * 4 + hd];
  float m = -1e30f, denom = 0.f, acc = 0.f;
  int i = beg;
  for (; i + 4 <= end; i += 4) {
    int s0 = csr_src[i + 0];
    int s1 = csr_src[i + 1];
    int s2 = csr_src[i + 2];
    int s3 = csr_src[i + 3];
    float l0 = lg0[(size_t)(i + 0) * 4 + hd] + ald;
    float l1 = lg0[(size_t)(i + 1) * 4 + hd] + ald;
    float l2 = lg0[(size_t)(i + 2) * 4 + hd] + ald;
    float l3 = lg0[(size_t)(i + 3) * 4 + hd] + ald;
    l0 = (l0 > 0.f) ? l0 : 0.2f * l0;
    l1 = (l1 > 0.f) ? l1 : 0.2f * l1;
    l2 = (l2 > 0.f) ? l2 : 0.2f * l2;
    l3 = (l3 > 0.f) ? l3 : 0.2f * l3;
    unsigned short x0 = xlb[(size_t)s0 * HC + lane];
    unsigned short x1 = xlb[(size_t)s1 * HC + lane];
    unsigned short x2 = xlb[(size_t)s2 * HC + lane];
    unsigned short x3 = xlb[(size_t)s3 * HC + lane];
    float mx = fmaxf(fmaxf(fmaxf(l0, l1), fmaxf(l2, l3)), m);
    float sc = __expf(m - mx);
    float p0 = __expf(l0 - mx);
    float p1 = __expf(l1 - mx);
    float p2 = __expf(l2 - mx);
    float p3 = __expf(l3 - mx);
    denom = denom * sc + ((p0 + p1) + (p2 + p3));
    acc = acc * sc + p0 * bf2f(x0) + p1 * bf2f(x1) + p2 * bf2f(x2) + p3 * bf2f(x3);
    m = mx;
  }
  for (; i < end; ++i) {
    int s = csr_src[i];
    float l = lg0[(size_t)i * 4 + hd] + ald;
    l = (l > 0.f) ? l : 0.2f * l;
    float mx = fmaxf(m, l);
    float sc = __expf(m - mx);
    float p = __expf(l - mx);
    denom = denom * sc + p;
    acc = acc * sc + p * bf2f(xlb[(size_t)s * HC + lane]);
    m = mx;
  }
  float hv = fmaxf(acc / denom + bias[lane], 0.f);
  if constexpr (!FUSE_PROJ) {
    outp[(size_t)n * HC + lane] = hv;
  } else {
    float pj[8];
#pragma unroll
    for (int j = 0; j < 8; ++j) pj[j] = hv * Wp[lane * PROJ + j];
#pragma unroll
    for (int off = 1; off < 64; off <<= 1) {
#pragma unroll
      for (int j = 0; j < 8; ++j) pj[j] += __shfl_xor(pj[j], off);
    }
    if (lane < 8) {
      float v = pj[0];
      v = (lane == 1) ? pj[1] : v;
      v = (lane == 2) ? pj[2] : v;
      v = (lane == 3) ? pj[3] : v;
      v = (lane == 4) ? pj[4] : v;
      v = (lane == 5) ? pj[5] : v;
      v = (lane == 6) ? pj[6] : v;
      v = (lane == 7) ? pj[7] : v;
      outp[(size_t)n * PROJ + lane] = fmaxf(v + bp[lane], 0.f);
    }
  }
}

// ---------------- fc_out stage 1: K-chunked partials ----------------
__global__ __launch_bounds__(256) void fc1_kernel(const float* __restrict__ p,
                                                  const float* __restrict__ Wo,
                                                  float* __restrict__ part) {
  __shared__ float sp[NGRAPH][250];
  int kc = blockIdx.x;   // 0..31, chunk of 250 K
  int ct = blockIdx.y;   // 0..3, 64 cols
  int tid = threadIdx.x;
  for (int i = tid; i < NGRAPH * 250; i += 256) {
    int g = i / 250, kk = i % 250;
    sp[g][kk] = p[(size_t)g * 8000 + kc * 250 + kk];
  }
  __syncthreads();
  int c = ct * 64 + (tid & 63);
  int kg = tid >> 6;   // wave id, wave-uniform
  float acc[NGRAPH] = {};
  for (int kk = kg; kk < 250; kk += 4) {
    float w = Wo[(size_t)(kc * 250 + kk) * OUT_DIM + c];
#pragma unroll
    for (int g = 0; g < NGRAPH; ++g) acc[g] = fmaf(sp[g][kk], w, acc[g]);
  }
  int ch = kc * 4 + kg;   // 0..127
#pragma unroll
  for (int g = 0; g < NGRAPH; ++g)
    part[((size_t)ch * NGRAPH + g) * OUT_DIM + c] = acc[g];
}

// ---------------- fc_out stage 2: reduce + bias ----------------
__global__ __launch_bounds__(256) void fc2_kernel(const float* __restrict__ part,
                                                  const float* __restrict__ bo,
                                                  float* __restrict__ out) {
  int i = blockIdx.x * 256 + threadIdx.x;   // 32*256 = 8192 exact
  int g = i >> 8, c = i & 255;
  float s = bo[c];
  for (int ch = 0; ch < 128; ++ch) s += part[((size_t)ch * NGRAPH + g) * OUT_DIM + c];
  out[i] = s;
}

extern "C" void kernel_launch(void* const* d_in, const int* in_sizes, int n_in,
                              void* d_out, int out_size, void* d_ws, size_t ws_size,
                              hipStream_t stream) {
  const float* x         = (const float*)d_in[0];
  const float* edge_attr = (const float*)d_in[1];
  const float* W0        = (const float*)d_in[2];
  const float* a_s0      = (const float*)d_in[3];
  const float* a_d0      = (const float*)d_in[4];
  const float* W_e0      = (const float*)d_in[5];
  const float* a_e0      = (const float*)d_in[6];
  const float* b0        = (const float*)d_in[7];
  const float* Wg        = (const float*)d_in[8];
  const float* a_sg      = (const float*)d_in[9];
  const float* a_dg      = (const float*)d_in[10];
  const float* W_eg      = (const float*)d_in[11];
  const float* a_eg      = (const float*)d_in[12];
  const float* bg        = (const float*)d_in[13];
  const float* Wp        = (const float*)d_in[14];
  const float* bp        = (const float*)d_in[15];
  const float* Wo        = (const float*)d_in[16];
  const float* bo        = (const float*)d_in[17];
  const int*   ei        = (const int*)d_in[18];

  char* base = (char*)d_ws;
  size_t off = 0;
  auto alloc = [&](size_t bytes) -> void* {
    void* ptr = base + off;
    off = (off + bytes + 255) & ~(size_t)255;
    return ptr;
  };
  int*            deg       = (int*)alloc((size_t)N_NODES * 4);
  int*            offs      = (int*)alloc((size_t)(N_NODES + 1) * 4);
  int*            nxt       = (int*)alloc((size_t)N_NODES * 4);
  int*            bsum      = (int*)alloc(128 * 4);
  int*            boffs     = (int*)alloc(128 * 4);
  int*            csr_src   = (int*)alloc((size_t)EF_EDGES * 4);
  int*            csr_eid   = (int*)alloc((size_t)EF_EDGES * 4);
  int*            csr_pos   = (int*)alloc((size_t)EF_EDGES * 4);
  float*          loop_attr = (float*)alloc((size_t)N_NODES * 16 * 4);
  float*          lg0       = (float*)alloc((size_t)EF_EDGES * 4 * 4);
  unsigned short* xlb       = (unsigned short*)alloc((size_t)N_NODES * HC * 2);
  float*          al_s      = (float*)alloc((size_t)N_NODES * 4 * 4);
  float*          al_d      = (float*)alloc((size_t)N_NODES * 4 * 4);
  float*          hA        = (float*)alloc((size_t)N_NODES * HC * 4);
  float*          hB        = (float*)alloc((size_t)N_NODES * HC * 4);
  float*          pbuf      = (float*)alloc((size_t)N_NODES * PROJ * 4);
  float*          part      = (float*)alloc((size_t)128 * NGRAPH * OUT_DIM * 4);

  // ---- graph preprocessing (dst is layer-invariant) ----
  hipMemsetAsync(deg, 0, (size_t)N_NODES * 4, stream);
  deg_kernel<<<E_EDGES / 256, 256, 0, stream>>>(ei, deg);
  scan1_kernel<<<N_NODES / 256, 256, 0, stream>>>(deg, offs, bsum);
  scan2_kernel<<<1, 128, 0, stream>>>(bsum, boffs, offs);
  scan3_kernel<<<N_NODES / 256, 256, 0, stream>>>(boffs, offs, nxt);
  fill_kernel<<<EF_EDGES / 256, 256, 0, stream>>>(ei, nxt, csr_src, csr_eid, csr_pos);
  loopattr_kernel<<<N_NODES / 4, 256, 0, stream>>>(offs, csr_eid, edge_attr, loop_attr);

  // ---- layer 0: x(128) -> hA ----
  transform_kernel<FIN><<<N_NODES / 64, 256, 0, stream>>>(x, W0, a_s0, a_d0, xlb, al_s, al_d);
  logit_kernel<<<EF_EDGES / 256, 256, 0, stream>>>(edge_attr, loop_attr, W_e0, a_e0, ei, csr_pos, al_s, lg0);
  gather_kernel<0><<<N_NODES / 4, 256, 0, stream>>>(offs, csr_src, lg0, xlb, al_d, b0, Wp, bp, hA);

  // ---- layer 1: hA -> hB ----
  transform_kernel<HC><<<N_NODES / 64, 256, 0, stream>>>(hA, Wg, a_sg, a_dg, xlb, al_s, al_d);
  logit_kernel<<<EF_EDGES / 256, 256, 0, stream>>>(edge_attr, loop_attr, W_eg, a_eg, ei, csr_pos, al_s, lg0);
  gather_kernel<0><<<N_NODES / 4, 256, 0, stream>>>(offs, csr_src, lg0, xlb, al_d, bg, Wp, bp, hB);

  // ---- layer 2: hB -> pbuf (proj fused) ----
  transform_kernel<HC><<<N_NODES / 64, 256, 0, stream>>>(hB, Wg + HC * HC, a_sg + 64, a_dg + 64, xlb, al_s, al_d);
  logit_kernel<<<EF_EDGES / 256, 256, 0, stream>>>(edge_attr, loop_attr, W_eg + 16 * HC, a_eg + 64, ei, csr_pos, al_s, lg0);
  gather_kernel<1><<<N_NODES / 4, 256, 0, stream>>>(offs, csr_src, lg0, xlb, al_d, bg + 64, Wp, bp, pbuf);

  // ---- head ----
  fc1_kernel<<<dim3(32, 4), 256, 0, stream>>>(pbuf, Wo, part);
  fc2_kernel<<<NGRAPH, 256, 0, stream>>>(part, bo, (float*)d_out);
}

// Round 4
// 277.949 us; speedup vs baseline: 1.5917x; 1.0032x over previous
//
#include <hip/hip_runtime.h>
#include <hip/hip_bf16.h>

#define N_NODES 32000
#define FIN     128
#define E_EDGES 512000
#define EF_EDGES 544000
#define HC      64
#define NGRAPH  32
#define PROJ    8
#define OUT_DIM 256

// fp32 -> bf16 (RTNE) and back
static __device__ inline unsigned short f2bf(float f) {
  unsigned int x = __float_as_uint(f);
  unsigned int r = (x + 0x7fffu + ((x >> 16) & 1u)) >> 16;
  return (unsigned short)r;
}
static __device__ inline float bf2f(unsigned short u) {
  return __uint_as_float((unsigned int)u << 16);
}

// ---------------- zero deg (avoid hipMemsetAsync fill node: 41us -> ~2us) ----------------
__global__ __launch_bounds__(256) void zero_kernel(int* __restrict__ deg) {
  deg[blockIdx.x * 256 + threadIdx.x] = 0;
}

// ---------------- degree count (int atomics) ----------------
__global__ __launch_bounds__(256) void deg_kernel(const int* __restrict__ ei,
                                                  int* __restrict__ deg) {
  int e = blockIdx.x * 256 + threadIdx.x;   // grid exactly E/256
  atomicAdd(&deg[ei[E_EDGES + e]], 1);
}

// ---------------- multi-block scan of deg+1 ----------------
// phase 1: per-block exclusive scan + block sums
__global__ __launch_bounds__(256) void scan1_kernel(const int* __restrict__ deg,
                                                    int* __restrict__ offs,
                                                    int* __restrict__ bsum) {
  int idx = blockIdx.x * 256 + threadIdx.x;   // grid exactly 125
  int lane = threadIdx.x & 63;
  int w = threadIdx.x >> 6;
  int v = deg[idx] + 1;   // +1 self-loop
  int s = v;
#pragma unroll
  for (int off = 1; off < 64; off <<= 1) {
    int t = __shfl_up(s, off);
    if (lane >= off) s += t;
  }
  __shared__ int wsum[4];
  if (lane == 63) wsum[w] = s;
  __syncthreads();
  int add = 0;
#pragma unroll
  for (int i = 0; i < 4; ++i) add += (i < w) ? wsum[i] : 0;
  int incl = s + add;
  offs[idx] = incl - v;   // exclusive within block
  if (threadIdx.x == 255) bsum[blockIdx.x] = incl;
}

// phase 2: scan the 125 block sums (1 block)
__global__ __launch_bounds__(128) void scan2_kernel(const int* __restrict__ bsum,
                                                    int* __restrict__ boffs,
                                                    int* __restrict__ offs) {
  int t = threadIdx.x;
  int lane = t & 63;
  int w = t >> 6;
  int v = (t < 125) ? bsum[t] : 0;
  int s = v;
#pragma unroll
  for (int off = 1; off < 64; off <<= 1) {
    int tt = __shfl_up(s, off);
    if (lane >= off) s += tt;
  }
  __shared__ int wsum[2];
  if (lane == 63) wsum[w] = s;
  __syncthreads();
  int incl = s + ((w == 1) ? wsum[0] : 0);
  if (t < 125) boffs[t] = incl - v;
  if (t == 127) offs[N_NODES] = incl;   // grand total = EF_EDGES
}

// phase 3: add block offsets, fill cursor array
__global__ __launch_bounds__(256) void scan3_kernel(const int* __restrict__ boffs,
                                                    int* __restrict__ offs,
                                                    int* __restrict__ nxt) {
  int idx = blockIdx.x * 256 + threadIdx.x;
  int o = offs[idx] + boffs[blockIdx.x];
  offs[idx] = o;
  nxt[idx] = o;
}

// ---------------- CSR fill (includes self-loops, eid>=E) + inverse map ----------------
__global__ __launch_bounds__(256) void fill_kernel(const int* __restrict__ ei,
                                                   int* __restrict__ nxt,
                                                   int* __restrict__ csr_src,
                                                   int* __restrict__ csr_eid,
                                                   int* __restrict__ csr_pos) {
  int e = blockIdx.x * 256 + threadIdx.x;   // grid exactly EF/256
  int s, d;
  if (e < E_EDGES) { s = ei[e]; d = ei[E_EDGES + e]; }
  else             { s = e - E_EDGES; d = s; }
  int pos = atomicAdd(&nxt[d], 1);
  csr_src[pos] = s;
  csr_eid[pos] = e;
  csr_pos[e] = pos;
}

// ---------------- self-loop attr = mean of incoming edge_attr ----------------
__global__ __launch_bounds__(256) void loopattr_kernel(const int* __restrict__ offs,
                                                       const int* __restrict__ csr_eid,
                                                       const float* __restrict__ ea,
                                                       float* __restrict__ loop_attr) {
  int lane = threadIdx.x & 63;
  int n = blockIdx.x * 4 + (threadIdx.x >> 6);
  int k = lane & 15, g = lane >> 4;
  int beg = offs[n], end = offs[n + 1];
  float s = 0.f;
  for (int i = beg + g; i < end; i += 4) {
    int e = csr_eid[i];
    if (e < E_EDGES) s += ea[(size_t)e * 16 + k];
  }
  s += __shfl_xor(s, 16);
  s += __shfl_xor(s, 32);
  int degv = end - beg - 1;  // real in-edges
  if (g == 0) loop_attr[(size_t)n * 16 + k] = s / fmaxf((float)degv, 1.f);
}

// ---------------- xl(bf16) = A @ W ; fused al_s/al_d epilogue ----------------
template <int K>
__global__ __launch_bounds__(256) void transform_kernel(const float* __restrict__ A,
                                                        const float* __restrict__ W,
                                                        const float* __restrict__ a_s,
                                                        const float* __restrict__ a_d,
                                                        unsigned short* __restrict__ xlb,
                                                        float* __restrict__ al_s,
                                                        float* __restrict__ al_d) {
  __shared__ float sW[64][64];
  __shared__ float sA[64][65];
  int tid = threadIdx.x;
  int row0 = blockIdx.x * 64;
  int tx = tid & 15, ty = tid >> 4;
  int c0 = tx * 4, r0 = ty * 4;
  float acc[4][4] = {};
  for (int kc = 0; kc < K; kc += 64) {
    for (int i = tid; i < 1024; i += 256) {
      int kk = i >> 4, c4 = (i & 15) * 4;
      *(float4*)&sW[kk][c4] = *(const float4*)&W[(size_t)(kc + kk) * HC + c4];
    }
    for (int i = tid; i < 1024; i += 256) {
      int r = i >> 4, k4 = (i & 15) * 4;
      float4 v = *(const float4*)&A[(size_t)(row0 + r) * K + kc + k4];
      sA[r][k4 + 0] = v.x; sA[r][k4 + 1] = v.y;
      sA[r][k4 + 2] = v.z; sA[r][k4 + 3] = v.w;
    }
    __syncthreads();
#pragma unroll 8
    for (int kk = 0; kk < 64; ++kk) {
      float4 w = *(float4*)&sW[kk][c0];
      float a0 = sA[r0 + 0][kk];
      float a1 = sA[r0 + 1][kk];
      float a2 = sA[r0 + 2][kk];
      float a3 = sA[r0 + 3][kk];
      acc[0][0] = fmaf(a0, w.x, acc[0][0]); acc[0][1] = fmaf(a0, w.y, acc[0][1]);
      acc[0][2] = fmaf(a0, w.z, acc[0][2]); acc[0][3] = fmaf(a0, w.w, acc[0][3]);
      acc[1][0] = fmaf(a1, w.x, acc[1][0]); acc[1][1] = fmaf(a1, w.y, acc[1][1]);
      acc[1][2] = fmaf(a1, w.z, acc[1][2]); acc[1][3] = fmaf(a1, w.w, acc[1][3]);
      acc[2][0] = fmaf(a2, w.x, acc[2][0]); acc[2][1] = fmaf(a2, w.y, acc[2][1]);
      acc[2][2] = fmaf(a2, w.z, acc[2][2]); acc[2][3] = fmaf(a2, w.w, acc[2][3]);
      acc[3][0] = fmaf(a3, w.x, acc[3][0]); acc[3][1] = fmaf(a3, w.y, acc[3][1]);
      acc[3][2] = fmaf(a3, w.z, acc[3][2]); acc[3][3] = fmaf(a3, w.w, acc[3][3]);
    }
    __syncthreads();
  }
  float asv[4], adv[4];
#pragma unroll
  for (int j = 0; j < 4; ++j) { asv[j] = a_s[c0 + j]; adv[j] = a_d[c0 + j]; }
  int hd = tx >> 2;
#pragma unroll
  for (int i = 0; i < 4; ++i) {
    int r = row0 + r0 + i;
    ushort4 u = make_ushort4(f2bf(acc[i][0]), f2bf(acc[i][1]),
                             f2bf(acc[i][2]), f2bf(acc[i][3]));
    *(ushort4*)&xlb[(size_t)r * HC + c0] = u;
    float ps = acc[i][0] * asv[0] + acc[i][1] * asv[1] + acc[i][2] * asv[2] + acc[i][3] * asv[3];
    float pd = acc[i][0] * adv[0] + acc[i][1] * adv[1] + acc[i][2] * adv[2] + acc[i][3] * adv[3];
    ps += __shfl_xor(ps, 1); ps += __shfl_xor(ps, 2);
    pd += __shfl_xor(pd, 1); pd += __shfl_xor(pd, 2);
    if ((tx & 3) == 0) {
      al_s[(size_t)r * 4 + hd] = ps;
      al_d[(size_t)r * 4 + hd] = pd;
    }
  }
}

// ---------------- lg0[pos] = al_s[src] + ea_f @ M_e  (CSR-ordered) ----------------
__global__ __launch_bounds__(256) void logit_kernel(const float* __restrict__ edge_attr,
                                                    const float* __restrict__ loop_attr,
                                                    const float* __restrict__ W_e,
                                                    const float* __restrict__ a_e,
                                                    const int* __restrict__ ei,
                                                    const int* __restrict__ csr_pos,
                                                    const float* __restrict__ al_s,
                                                    float* __restrict__ lg0) {
  __shared__ float sMe[16][4];
  int tid = threadIdx.x;
  if (tid < 64) {
    int d = tid >> 2, h = tid & 3;
    float s = 0.f;
#pragma unroll
    for (int c = 0; c < 16; ++c) s += W_e[d * HC + h * 16 + c] * a_e[h * 16 + c];
    sMe[d][h] = s;
  }
  __syncthreads();
  int e = blockIdx.x * 256 + tid;   // grid exactly EF/256
  int src;
  const float* ea;
  if (e < E_EDGES) { src = ei[e];          ea = &edge_attr[(size_t)e * 16]; }
  else             { src = e - E_EDGES;    ea = &loop_attr[(size_t)(e - E_EDGES) * 16]; }
  float4 v0 = *(const float4*)(ea + 0);
  float4 v1 = *(const float4*)(ea + 4);
  float4 v2 = *(const float4*)(ea + 8);
  float4 v3 = *(const float4*)(ea + 12);
  float4 als = *(const float4*)&al_s[(size_t)src * 4];
  float r[4];
#pragma unroll
  for (int h = 0; h < 4; ++h) {
    r[h] = v0.x * sMe[0][h] + v0.y * sMe[1][h] + v0.z * sMe[2][h] + v0.w * sMe[3][h] +
           v1.x * sMe[4][h] + v1.y * sMe[5][h] + v1.z * sMe[6][h] + v1.w * sMe[7][h] +
           v2.x * sMe[8][h] + v2.y * sMe[9][h] + v2.z * sMe[10][h] + v2.w * sMe[11][h] +
           v3.x * sMe[12][h] + v3.y * sMe[13][h] + v3.z * sMe[14][h] + v3.w * sMe[15][h];
  }
  int pos = csr_pos[e];
  *(float4*)&lg0[(size_t)pos * 4] =
      make_float4(r[0] + als.x, r[1] + als.y, r[2] + als.z, r[3] + als.w);
}

// ---------------- one-pass online softmax + aggregation (wave per node) ----------------
template <int FUSE_PROJ>
__global__ __launch_bounds__(256) void gather_kernel(const int* __restrict__ offs,
                                                     const int* __restrict__ csr_src,
                                                     const float* __restrict__ lg0,
                                                     const unsigned short* __restrict__ xlb,
                                                     const float* __restrict__ al_d,
                                                     const float* __restrict__ bias,
                                                     const float* __restrict__ Wp,
                                                     const float* __restrict__ bp,
                                                     float* __restrict__ outp) {
  int lane = threadIdx.x & 63;
  int n = blockIdx.x * 4 + (threadIdx.x >> 6);
  int hd = lane >> 4;
  int beg = offs[n], end = offs[n + 1];
  float ald = al_d[(size_t)n * 4 + hd];
  float m = -1e30f, denom = 0.f, acc = 0.f;
  int i = beg;
  for (; i + 4 <= end; i += 4) {
    int s0 = csr_src[i + 0];
    int s1 = csr_src[i + 1];
    int s2 = csr_src[i + 2];
    int s3 = csr_src[i + 3];
    float l0 = lg0[(size_t)(i + 0) * 4 + hd] + ald;
    float l1 = lg0[(size_t)(i + 1) * 4 + hd] + ald;
    float l2 = lg0[(size_t)(i + 2) * 4 + hd] + ald;
    float l3 = lg0[(size_t)(i + 3) * 4 + hd] + ald;
    l0 = (l0 > 0.f) ? l0 : 0.2f * l0;
    l1 = (l1 > 0.f) ? l1 : 0.2f * l1;
    l2 = (l2 > 0.f) ? l2 : 0.2f * l2;
    l3 = (l3 > 0.f) ? l3 : 0.2f * l3;
    unsigned short x0 = xlb[(size_t)s0 * HC + lane];
    unsigned short x1 = xlb[(size_t)s1 * HC + lane];
    unsigned short x2 = xlb[(size_t)s2 * HC + lane];
    unsigned short x3 = xlb[(size_t)s3 * HC + lane];
    float mx = fmaxf(fmaxf(fmaxf(l0, l1), fmaxf(l2, l3)), m);
    float sc = __expf(m - mx);
    float p0 = __expf(l0 - mx);
    float p1 = __expf(l1 - mx);
    float p2 = __expf(l2 - mx);
    float p3 = __expf(l3 - mx);
    denom = denom * sc + ((p0 + p1) + (p2 + p3));
    acc = acc * sc + p0 * bf2f(x0) + p1 * bf2f(x1) + p2 * bf2f(x2) + p3 * bf2f(x3);
    m = mx;
  }
  for (; i < end; ++i) {
    int s = csr_src[i];
    float l = lg0[(size_t)i * 4 + hd] + ald;
    l = (l > 0.f) ? l : 0.2f * l;
    float mx = fmaxf(m, l);
    float sc = __expf(m - mx);
    float p = __expf(l - mx);
    denom = denom * sc + p;
    acc = acc * sc + p * bf2f(xlb[(size_t)s * HC + lane]);
    m = mx;
  }
  float hv = fmaxf(acc / denom + bias[lane], 0.f);
  if constexpr (!FUSE_PROJ) {
    outp[(size_t)n * HC + lane] = hv;
  } else {
    float pj[8];
#pragma unroll
    for (int j = 0; j < 8; ++j) pj[j] = hv * Wp[lane * PROJ + j];
#pragma unroll
    for (int off = 1; off < 64; off <<= 1) {
#pragma unroll
      for (int j = 0; j < 8; ++j) pj[j] += __shfl_xor(pj[j], off);
    }
    if (lane < 8) {
      float v = pj[0];
      v = (lane == 1) ? pj[1] : v;
      v = (lane == 2) ? pj[2] : v;
      v = (lane == 3) ? pj[3] : v;
      v = (lane == 4) ? pj[4] : v;
      v = (lane == 5) ? pj[5] : v;
      v = (lane == 6) ? pj[6] : v;
      v = (lane == 7) ? pj[7] : v;
      outp[(size_t)n * PROJ + lane] = fmaxf(v + bp[lane], 0.f);
    }
  }
}

// ---------------- fc_out stage 1: K-chunked partials ----------------
__global__ __launch_bounds__(256) void fc1_kernel(const float* __restrict__ p,
                                                  const float* __restrict__ Wo,
                                                  float* __restrict__ part) {
  __shared__ float sp[NGRAPH][250];
  int kc = blockIdx.x;   // 0..31, chunk of 250 K
  int ct = blockIdx.y;   // 0..3, 64 cols
  int tid = threadIdx.x;
  for (int i = tid; i < NGRAPH * 250; i += 256) {
    int g = i / 250, kk = i % 250;
    sp[g][kk] = p[(size_t)g * 8000 + kc * 250 + kk];
  }
  __syncthreads();
  int c = ct * 64 + (tid & 63);
  int kg = tid >> 6;   // wave id, wave-uniform
  float acc[NGRAPH] = {};
  for (int kk = kg; kk < 250; kk += 4) {
    float w = Wo[(size_t)(kc * 250 + kk) * OUT_DIM + c];
#pragma unroll
    for (int g = 0; g < NGRAPH; ++g) acc[g] = fmaf(sp[g][kk], w, acc[g]);
  }
  int ch = kc * 4 + kg;   // 0..127
#pragma unroll
  for (int g = 0; g < NGRAPH; ++g)
    part[((size_t)ch * NGRAPH + g) * OUT_DIM + c] = acc[g];
}

// ---------------- fc_out stage 2: reduce + bias ----------------
__global__ __launch_bounds__(256) void fc2_kernel(const float* __restrict__ part,
                                                  const float* __restrict__ bo,
                                                  float* __restrict__ out) {
  int i = blockIdx.x * 256 + threadIdx.x;   // 32*256 = 8192 exact
  int g = i >> 8, c = i & 255;
  float s = bo[c];
  for (int ch = 0; ch < 128; ++ch) s += part[((size_t)ch * NGRAPH + g) * OUT_DIM + c];
  out[i] = s;
}

extern "C" void kernel_launch(void* const* d_in, const int* in_sizes, int n_in,
                              void* d_out, int out_size, void* d_ws, size_t ws_size,
                              hipStream_t stream) {
  const float* x         = (const float*)d_in[0];
  const float* edge_attr = (const float*)d_in[1];
  const float* W0        = (const float*)d_in[2];
  const float* a_s0      = (const float*)d_in[3];
  const float* a_d0      = (const float*)d_in[4];
  const float* W_e0      = (const float*)d_in[5];
  const float* a_e0      = (const float*)d_in[6];
  const float* b0        = (const float*)d_in[7];
  const float* Wg        = (const float*)d_in[8];
  const float* a_sg      = (const float*)d_in[9];
  const float* a_dg      = (const float*)d_in[10];
  const float* W_eg      = (const float*)d_in[11];
  const float* a_eg      = (const float*)d_in[12];
  const float* bg        = (const float*)d_in[13];
  const float* Wp        = (const float*)d_in[14];
  const float* bp        = (const float*)d_in[15];
  const float* Wo        = (const float*)d_in[16];
  const float* bo        = (const float*)d_in[17];
  const int*   ei        = (const int*)d_in[18];

  char* base = (char*)d_ws;
  size_t off = 0;
  auto alloc = [&](size_t bytes) -> void* {
    void* ptr = base + off;
    off = (off + bytes + 255) & ~(size_t)255;
    return ptr;
  };
  int*            deg       = (int*)alloc((size_t)N_NODES * 4);
  int*            offs      = (int*)alloc((size_t)(N_NODES + 1) * 4);
  int*            nxt       = (int*)alloc((size_t)N_NODES * 4);
  int*            bsum      = (int*)alloc(128 * 4);
  int*            boffs     = (int*)alloc(128 * 4);
  int*            csr_src   = (int*)alloc((size_t)EF_EDGES * 4);
  int*            csr_eid   = (int*)alloc((size_t)EF_EDGES * 4);
  int*            csr_pos   = (int*)alloc((size_t)EF_EDGES * 4);
  float*          loop_attr = (float*)alloc((size_t)N_NODES * 16 * 4);
  float*          lg0       = (float*)alloc((size_t)EF_EDGES * 4 * 4);
  unsigned short* xlb       = (unsigned short*)alloc((size_t)N_NODES * HC * 2);
  float*          al_s      = (float*)alloc((size_t)N_NODES * 4 * 4);
  float*          al_d      = (float*)alloc((size_t)N_NODES * 4 * 4);
  float*          hA        = (float*)alloc((size_t)N_NODES * HC * 4);
  float*          hB        = (float*)alloc((size_t)N_NODES * HC * 4);
  float*          pbuf      = (float*)alloc((size_t)N_NODES * PROJ * 4);
  float*          part      = (float*)alloc((size_t)128 * NGRAPH * OUT_DIM * 4);

  // ---- graph preprocessing (dst is layer-invariant) ----
  zero_kernel<<<N_NODES / 256, 256, 0, stream>>>(deg);
  deg_kernel<<<E_EDGES / 256, 256, 0, stream>>>(ei, deg);
  scan1_kernel<<<N_NODES / 256, 256, 0, stream>>>(deg, offs, bsum);
  scan2_kernel<<<1, 128, 0, stream>>>(bsum, boffs, offs);
  scan3_kernel<<<N_NODES / 256, 256, 0, stream>>>(boffs, offs, nxt);
  fill_kernel<<<EF_EDGES / 256, 256, 0, stream>>>(ei, nxt, csr_src, csr_eid, csr_pos);
  loopattr_kernel<<<N_NODES / 4, 256, 0, stream>>>(offs, csr_eid, edge_attr, loop_attr);

  // ---- layer 0: x(128) -> hA ----
  transform_kernel<FIN><<<N_NODES / 64, 256, 0, stream>>>(x, W0, a_s0, a_d0, xlb, al_s, al_d);
  logit_kernel<<<EF_EDGES / 256, 256, 0, stream>>>(edge_attr, loop_attr, W_e0, a_e0, ei, csr_pos, al_s, lg0);
  gather_kernel<0><<<N_NODES / 4, 256, 0, stream>>>(offs, csr_src, lg0, xlb, al_d, b0, Wp, bp, hA);

  // ---- layer 1: hA -> hB ----
  transform_kernel<HC><<<N_NODES / 64, 256, 0, stream>>>(hA, Wg, a_sg, a_dg, xlb, al_s, al_d);
  logit_kernel<<<EF_EDGES / 256, 256, 0, stream>>>(edge_attr, loop_attr, W_eg, a_eg, ei, csr_pos, al_s, lg0);
  gather_kernel<0><<<N_NODES / 4, 256, 0, stream>>>(offs, csr_src, lg0, xlb, al_d, bg, Wp, bp, hB);

  // ---- layer 2: hB -> pbuf (proj fused) ----
  transform_kernel<HC><<<N_NODES / 64, 256, 0, stream>>>(hB, Wg + HC * HC, a_sg + 64, a_dg + 64, xlb, al_s, al_d);
  logit_kernel<<<EF_EDGES / 256, 256, 0, stream>>>(edge_attr, loop_attr, W_eg + 16 * HC, a_eg + 64, ei, csr_pos, al_s, lg0);
  gather_kernel<1><<<N_NODES / 4, 256, 0, stream>>>(offs, csr_src, lg0, xlb, al_d, bg + 64, Wp, bp, pbuf);

  // ---- head ----
  fc1_kernel<<<dim3(32, 4), 256, 0, stream>>>(pbuf, Wo, part);
  fc2_kernel<<<NGRAPH, 256, 0, stream>>>(part, bo, (float*)d_out);
}